// Round 1
// baseline (3113.556 us; speedup 1.0000x reference)
//
#include <hip/hip_runtime.h>
#include <math.h>

#define HW 4096

// ---------------- norms: inv[b,i] = 1/sqrt(sum_c f[b,c,i]^2 + 1e-6) ----------------
__global__ __launch_bounds__(256) void norm_partial(const float* __restrict__ f, int C,
                                                    float* __restrict__ part) {
    int i = blockIdx.x * 256 + threadIdx.x;   // 0..4095
    int b = blockIdx.y;                        // 0..1
    int cz = blockIdx.z;                       // 0..7
    int chunk = C >> 3;
    const float* p = f + ((size_t)b * C + (size_t)cz * chunk) * HW + i;
    float s = 0.f;
    for (int c = 0; c < chunk; ++c) {
        float v = p[(size_t)c * HW];
        s = fmaf(v, v, s);
    }
    part[(cz * 2 + b) * HW + i] = s;
}

__global__ __launch_bounds__(256) void norm_finalize(const float* __restrict__ part,
                                                     float* __restrict__ inv) {
    int idx = blockIdx.x * 256 + threadIdx.x;  // 0..32767  (4 tensors x 8192)
    int tensor = idx >> 13;
    int pos = idx & 8191;
    const float* pt = part + (size_t)tensor * 65536;
    float s = 0.f;
#pragma unroll
    for (int cz = 0; cz < 8; ++cz) s += pt[cz * 8192 + pos];
    inv[idx] = 1.0f / sqrtf(s + 1e-6f);
}

// ---------------- fused correlation GEMM ----------------
// M[b,j,i] (op): relu( (sum_c A[b,c,j]*B[b,c,i]) * invA[b,j] * invB[b,i] )
// multiply=0: M = relu(...)      (level 3)
// multiply=1: M *= relu(...)     (level 4)
__global__ __launch_bounds__(256) void corr_gemm(const float* __restrict__ A,
                                                 const float* __restrict__ B,
                                                 const float* __restrict__ invA,
                                                 const float* __restrict__ invB,
                                                 float* __restrict__ M,
                                                 int C, int multiply) {
    __shared__ float As[16][128];
    __shared__ float Bs[16][128];
    const int tid = threadIdx.x;
    const int b = blockIdx.z;
    const int j0 = blockIdx.y * 128;
    const int i0 = blockIdx.x * 128;
    const float* Ab = A + (size_t)b * C * HW;
    const float* Bb = B + (size_t)b * C * HW;

    const int r0 = (tid * 4) >> 7;   // 0..7
    const int c0 = (tid * 4) & 127;
    const float* ap = Ab + (size_t)r0 * HW + (j0 + c0);
    const float* bp = Bb + (size_t)r0 * HW + (i0 + c0);

    float acc[8][8];
#pragma unroll
    for (int r = 0; r < 8; ++r)
#pragma unroll
        for (int c = 0; c < 8; ++c) acc[r][c] = 0.f;

    // stage k0 = 0
    float4 pa0 = *(const float4*)(ap);
    float4 pa1 = *(const float4*)(ap + (size_t)8 * HW);
    float4 pb0 = *(const float4*)(bp);
    float4 pb1 = *(const float4*)(bp + (size_t)8 * HW);
    *(float4*)&As[r0][c0] = pa0;
    *(float4*)&As[r0 + 8][c0] = pa1;
    *(float4*)&Bs[r0][c0] = pb0;
    *(float4*)&Bs[r0 + 8][c0] = pb1;
    __syncthreads();

    const int ty = tid >> 4, tx = tid & 15;

    for (int k0 = 0;;) {
        int kn = k0 + 16;
        bool have_next = (kn < C);
        if (have_next) {   // prefetch next K-tile to registers (hides latency behind FMAs)
            const float* an = ap + (size_t)kn * HW;
            const float* bn = bp + (size_t)kn * HW;
            pa0 = *(const float4*)(an);
            pa1 = *(const float4*)(an + (size_t)8 * HW);
            pb0 = *(const float4*)(bn);
            pb1 = *(const float4*)(bn + (size_t)8 * HW);
        }
#pragma unroll
        for (int kk = 0; kk < 16; ++kk) {
            float4 af0 = *(const float4*)&As[kk][ty * 8];
            float4 af1 = *(const float4*)&As[kk][ty * 8 + 4];
            float4 bf0 = *(const float4*)&Bs[kk][tx * 8];
            float4 bf1 = *(const float4*)&Bs[kk][tx * 8 + 4];
            float a[8]  = {af0.x, af0.y, af0.z, af0.w, af1.x, af1.y, af1.z, af1.w};
            float bb[8] = {bf0.x, bf0.y, bf0.z, bf0.w, bf1.x, bf1.y, bf1.z, bf1.w};
#pragma unroll
            for (int r = 0; r < 8; ++r)
#pragma unroll
                for (int c = 0; c < 8; ++c)
                    acc[r][c] = fmaf(a[r], bb[c], acc[r][c]);
        }
        if (!have_next) break;
        __syncthreads();
        *(float4*)&As[r0][c0] = pa0;
        *(float4*)&As[r0 + 8][c0] = pa1;
        *(float4*)&Bs[r0][c0] = pb0;
        *(float4*)&Bs[r0 + 8][c0] = pb1;
        __syncthreads();
        k0 = kn;
    }

    // epilogue: scale by norms, relu, (optionally multiply into existing M), store
    const int jb = j0 + ty * 8;
    const int ib = i0 + tx * 8;
    float sA[8], sB[8];
#pragma unroll
    for (int r = 0; r < 8; ++r) sA[r] = invA[b * HW + jb + r];
#pragma unroll
    for (int c = 0; c < 8; ++c) sB[c] = invB[b * HW + ib + c];
#pragma unroll
    for (int r = 0; r < 8; ++r) {
        float* mp = M + ((size_t)b * HW + (size_t)(jb + r)) * HW + ib;
        float o[8];
#pragma unroll
        for (int c = 0; c < 8; ++c) o[c] = fmaxf(acc[r][c] * sA[r] * sB[c], 0.f);
        if (multiply) {
            float4 m0 = *(const float4*)mp;
            float4 m1 = *(const float4*)(mp + 4);
            o[0] *= m0.x; o[1] *= m0.y; o[2] *= m0.z; o[3] *= m0.w;
            o[4] *= m1.x; o[5] *= m1.y; o[6] *= m1.z; o[7] *= m1.w;
        }
        float4 w0 = {o[0], o[1], o[2], o[3]};
        float4 w1 = {o[4], o[5], o[6], o[7]};
        *(float4*)mp = w0;
        *(float4*)(mp + 4) = w1;
    }
}

// ---------------- per-line soft-argmax reduction ----------------
// colmode=1: line = column i of M (s2t, output offset 0 / flow at 16384)
// colmode=0: line = row    c of M (t2s, output offset 32768 / flow at 49152)
// Key identities: argmax is invariant to the positive per-line scale; since
// gauss(argmax)=1 and all values>=0, max of masked values == vmax.
__global__ __launch_bounds__(256) void soft_argmax(const float* __restrict__ M,
                                                   float* __restrict__ out,
                                                   int colmode) {
    __shared__ float buf[HW];
    __shared__ float rv[256];
    __shared__ float rs[256];
    __shared__ int ri[256];
    const int tid = threadIdx.x;
    const int b = blockIdx.y;
    int line;
    if (colmode) {
        int bx = blockIdx.x;                 // XCD swizzle: 512-col contiguous span per XCD
        line = ((bx & 7) << 9) | (bx >> 3);  // keeps 16-col cache lines within one XCD's L2
    } else {
        line = blockIdx.x;
    }
    const float* base = M + (size_t)b * HW * HW;
    if (colmode) {
        for (int j = tid; j < HW; j += 256) buf[j] = base[(size_t)j * HW + line];
    } else {
        const float* row = base + (size_t)line * HW;
        for (int j4 = tid * 4; j4 < HW; j4 += 1024)
            *(float4*)&buf[j4] = *(const float4*)&row[j4];
    }
    __syncthreads();

    // pass 1: sum of squares + argmax (first-index tie-break to match jnp.argmax)
    float ss = 0.f, mx = -1.f;
    int mi = 0;
    for (int j = tid; j < HW; j += 256) {
        float v = buf[j];
        ss = fmaf(v, v, ss);
        if (v > mx) { mx = v; mi = j; }
    }
    rv[tid] = mx; ri[tid] = mi; rs[tid] = ss;
    __syncthreads();
    for (int s = 128; s > 0; s >>= 1) {
        if (tid < s) {
            rs[tid] += rs[tid + s];
            float v2 = rv[tid + s];
            int i2 = ri[tid + s];
            if (v2 > rv[tid] || (v2 == rv[tid] && i2 < ri[tid])) { rv[tid] = v2; ri[tid] = i2; }
        }
        __syncthreads();
    }
    const float inv = 1.0f / sqrtf(rs[0] + 1e-6f);
    const int amax = ri[0];
    const float vmax = rv[0] * inv;
    const float ax = (float)(amax & 63);
    const float ay = (float)(amax >> 6);

    // pass 2: gaussian-masked softmax expectation over normalized coords
    float se = 0.f, sx = 0.f, sy = 0.f;
    for (int j = tid; j < HW; j += 256) {
        int x2 = j & 63, y2 = j >> 6;
        float dx = (float)x2 - ax, dy = (float)y2 - ay;
        float g = __expf(-(dx * dx + dy * dy) * 0.02f);   // 1/(2*sigma^2) = 0.02
        float v = g * buf[j] * inv;
        float e = __expf(50.0f * (v - vmax));             // beta = 50
        se += e;
        sx = fmaf(e, fmaf((float)x2, 2.0f / 63.0f, -1.0f), sx);
        sy = fmaf(e, fmaf((float)y2, 2.0f / 63.0f, -1.0f), sy);
    }
    __syncthreads();
    rs[tid] = se; rv[tid] = sx; buf[tid] = sy;
    __syncthreads();
    for (int s = 128; s > 0; s >>= 1) {
        if (tid < s) {
            rs[tid] += rs[tid + s];
            rv[tid] += rv[tid + s];
            buf[tid] += buf[tid + s];
        }
        __syncthreads();
    }
    if (tid == 0) {
        float gx = rv[0] / rs[0];
        float gy = buf[0] / rs[0];
        size_t gbase = colmode ? 0 : 32768;
        size_t fbase = colmode ? 16384 : 49152;
        size_t p = gbase + ((size_t)b * HW + line) * 2;
        out[p] = gx;
        out[p + 1] = gy;
        // flows are identically zero (x - x); d_out is poisoned, so write them
        out[fbase + (size_t)(b * 2 + 0) * HW + line] = 0.f;
        out[fbase + (size_t)(b * 2 + 1) * HW + line] = 0.f;
    }
}

extern "C" void kernel_launch(void* const* d_in, const int* in_sizes, int n_in,
                              void* d_out, int out_size, void* d_ws, size_t ws_size,
                              hipStream_t stream) {
    const float* s3 = (const float*)d_in[0];
    const float* t3 = (const float*)d_in[1];
    const float* s4 = (const float*)d_in[2];
    const float* t4 = (const float*)d_in[3];
    float* out = (float*)d_out;
    float* ws = (float*)d_ws;

    // workspace layout (floats):
    // [0, 32768)        inv norms: s3, t3, s4, t4 (8192 each)
    // [32768, 294912)   norm partials (4 tensors x 8 chunks x 8192)
    // [294912, ...)     M: 2 x 4096 x 4096  (~134 MB)
    float* inv  = ws;
    float* part = ws + 32768;
    float* M    = ws + 294912;

    dim3 nb(16, 2, 8);
    norm_partial<<<nb, 256, 0, stream>>>(s3, 1024, part + 0 * 65536);
    norm_partial<<<nb, 256, 0, stream>>>(t3, 1024, part + 1 * 65536);
    norm_partial<<<nb, 256, 0, stream>>>(s4, 2048, part + 2 * 65536);
    norm_partial<<<nb, 256, 0, stream>>>(t4, 2048, part + 3 * 65536);
    norm_finalize<<<128, 256, 0, stream>>>(part, inv);

    dim3 gg(32, 32, 2);
    corr_gemm<<<gg, 256, 0, stream>>>(t3, s3, inv + 8192,  inv + 0,     M, 1024, 0);
    corr_gemm<<<gg, 256, 0, stream>>>(t4, s4, inv + 24576, inv + 16384, M, 2048, 1);

    dim3 rg(4096, 2);
    soft_argmax<<<rg, 256, 0, stream>>>(M, out, 1);  // columns -> grid_s2t / flow_s2t
    soft_argmax<<<rg, 256, 0, stream>>>(M, out, 0);  // rows    -> grid_t2s / flow_t2s
}